// Round 11
// baseline (475.185 us; speedup 1.0000x reference)
//
#include <hip/hip_runtime.h>

typedef __bf16 bf16;
typedef bf16 bf16x8 __attribute__((ext_vector_type(8)));
typedef float f32x4 __attribute__((ext_vector_type(4)));
typedef unsigned int uint;
typedef uint u32x4 __attribute__((ext_vector_type(4)));
typedef unsigned short u16x4 __attribute__((ext_vector_type(4)));
typedef unsigned short u16x8 __attribute__((ext_vector_type(8)));

constexpr int NT = 4096;   // sequence length N
// H = 64, B = 2

__device__ __forceinline__ bf16x8 ld8f(const float* p) {
    f32x4 a = *(const f32x4*)p;
    f32x4 b = *(const f32x4*)(p + 4);
    bf16x8 v;
    v[0] = (bf16)a[0]; v[1] = (bf16)a[1]; v[2] = (bf16)a[2]; v[3] = (bf16)a[3];
    v[4] = (bf16)b[0]; v[5] = (bf16)b[1]; v[6] = (bf16)b[2]; v[7] = (bf16)b[3];
    return v;
}

__device__ __forceinline__ uint pack2(float a, float b) {
    unsigned short ua = __builtin_bit_cast(unsigned short, (bf16)a);
    unsigned short ub = __builtin_bit_cast(unsigned short, (bf16)b);
    return (uint)ua | ((uint)ub << 16);
}

// non-temporal f32x4 load: masks are a 402MB single-use stream — bypass
// L3 retention (nt) so the stream doesn't churn Infinity Cache.
__device__ __forceinline__ f32x4 ldnt4(const float* p) {
    return __builtin_nontemporal_load((const f32x4*)p);
}

// ---------------------------------------------------------------------------
// Kernel 1: grid = 1536. slices 0..8: one projection each (q0,q1,q2,k0..k5);
// slices 9..11: bf16 transpose vT for one pred each.
// ---------------------------------------------------------------------------
__global__ __launch_bounds__(256) void prep_kernel(
    const float* __restrict__ h0, const float* __restrict__ h1, const float* __restrict__ h2,
    const float* __restrict__ Wq, const float* __restrict__ Wk,
    bf16* __restrict__ qn, bf16* __restrict__ kn, bf16* __restrict__ vT)
{
    __shared__ __align__(16) unsigned short tlds[4][16][72];
    const int tid = threadIdx.x, wid = tid >> 6, lane = tid & 63;
    const int l15 = lane & 15, quad = lane >> 4;
    const int bx = blockIdx.x;
    const int rt = bx & 127, sl = bx >> 7;       // slice 0..11
    const int g0 = rt * 64;
    const int grow = g0 + wid * 16 + l15;        // A-frag row (global b*N+n)
    const float* hs[3] = {h0, h1, h2};
    const int predmap[6] = {0, 2, 0, 1, 1, 2};

    if (sl >= 9) {
        // ---- transpose slice: vT[p][b][h][n] ----
        const int p = sl - 9;
        bf16x8 af[2];
#pragma unroll
        for (int hc = 0; hc < 2; hc++)
            af[hc] = ld8f(hs[p] + (size_t)grow * 64 + hc * 32 + quad * 8);
#pragma unroll
        for (int hc = 0; hc < 2; hc++)
            *(u16x8*)(&tlds[wid][l15][hc * 32 + quad * 8]) = __builtin_bit_cast(u16x8, af[hc]);
        unsigned short vals[16];
#pragma unroll
        for (int r = 0; r < 16; r++) vals[r] = tlds[wid][r][lane];
        uint us[8];
#pragma unroll
        for (int k = 0; k < 8; k++) us[k] = (uint)vals[2 * k] | ((uint)vals[2 * k + 1] << 16);
        const int gr0 = g0 + wid * 16;
        const int bb = gr0 >> 12, n0 = gr0 & 4095;
        uint* dst = (uint*)(vT + ((size_t)(p * 2 + bb) * 64 + lane) * NT + n0);
        u32x4 w0 = {us[0], us[1], us[2], us[3]};
        u32x4 w1 = {us[4], us[5], us[6], us[7]};
        *(u32x4*)dst = w0;
        *(u32x4*)(dst + 4) = w1;
        return;
    }

    // ---- projection slice ----
    const int pj = sl;
    const float* W = (pj < 3) ? (Wq + pj * 4096) : (Wk + (pj - 3) * 4096);
    const int src = (pj < 3) ? pj : predmap[pj - 3];
    bf16* outp = (pj < 3) ? (qn + (size_t)pj * 2 * NT * 64)
                          : (kn + (size_t)(pj - 3) * 2 * NT * 64);
    bf16x8 af[2];
#pragma unroll
    for (int hc = 0; hc < 2; hc++)
        af[hc] = ld8f(hs[src] + (size_t)grow * 64 + hc * 32 + quad * 8);

    f32x4 s[4];
#pragma unroll
    for (int it = 0; it < 4; it++) {
        f32x4 acc = {0.f, 0.f, 0.f, 0.f};
#pragma unroll
        for (int hc = 0; hc < 2; hc++) {
            bf16x8 wb = ld8f(W + (size_t)(it * 16 + l15) * 64 + hc * 32 + quad * 8);
            acc = __builtin_amdgcn_mfma_f32_16x16x32_bf16(af[hc], wb, acc, 0, 0, 0);
        }
        s[it] = acc;
    }
#pragma unroll
    for (int r = 0; r < 4; r++) {
        float ss = s[0][r] * s[0][r] + s[1][r] * s[1][r] + s[2][r] * s[2][r] + s[3][r] * s[3][r];
        ss += __shfl_xor(ss, 1); ss += __shfl_xor(ss, 2);
        ss += __shfl_xor(ss, 4); ss += __shfl_xor(ss, 8);
        float rn = rsqrtf(ss);
        s[0][r] *= rn; s[1][r] *= rn; s[2][r] *= rn; s[3][r] *= rn;
    }
    const int rowbase = g0 + wid * 16 + quad * 4;
#pragma unroll
    for (int it = 0; it < 4; it++)
#pragma unroll
        for (int r = 0; r < 4; r++)
            outp[(size_t)(rowbase + r) * 64 + it * 16 + l15] = (bf16)s[it][r];
}

// ---------------------------------------------------------------------------
// Kernel 2: masked cosine attention — R10 structure verbatim (fused NT fp32
// masks, single mask-register set, single LDS buffer, 2 barriers, permlane
// exchange, bf16 Pacc, in-kernel rowsums, VGPR 84).
// ONE change: JC=8 -> grid 1536 so 4 blocks/CU are resident (was exactly
// 3 blocks/CU at grid 768 — grid size, not resources, was the occupancy cap).
// grid = 6 edges * 32 q-tiles(128 rows) * JC.
// ---------------------------------------------------------------------------
template<int JC>
__global__ __launch_bounds__(256, 3) void attn_kernel(
    const bf16* __restrict__ qn, const bf16* __restrict__ kn, const bf16* __restrict__ vT,
    const float* __restrict__ m00, const float* __restrict__ m20, const float* __restrict__ m01,
    const float* __restrict__ m11, const float* __restrict__ m12, const float* __restrict__ m22,
    bf16* __restrict__ Pacc, float* __restrict__ rsO)
{
    __shared__ __align__(16) bf16 Klds[2][64][72];
    __shared__ __align__(16) bf16 Vlds[2][64][72];
    const int tid = threadIdx.x, wid = tid >> 6, lane = tid & 63;
    const int l15 = lane & 15, quad = lane >> 4;
    const int bx = blockIdx.x;
    const int e = bx / (32 * JC);
    const int rem = bx % (32 * JC);
    const int qt = rem / JC, jcv = rem % JC;
    const int qrow0 = qt * 128, wstrip = wid * 32;
    const int qtypemap[6] = {0, 0, 1, 1, 2, 2};
    const int predmap[6]  = {0, 2, 0, 1, 1, 2};
    const float* masks[6] = {m00, m20, m01, m11, m12, m22};
    const float* __restrict__ mask = masks[e];
    const int qtv = qtypemap[e], pv = predmap[e];
    constexpr int JSPAN = NT / JC;
    constexpr int NI = JSPAN / 64;
    const int jbeg = jcv * JSPAN;

    // per-thread staging line mapping (4 K lines + 4 V lines per thread)
    int s_b[4], s_jl[4], s_ch[4];
#pragma unroll
    for (int i = 0; i < 4; i++) {
        int u = tid + 256 * i;
        s_b[i] = u >> 9; s_jl[i] = (u >> 3) & 63; s_ch[i] = u & 7;
    }

    // Q fragments (stage-1 B-operand), register resident
    bf16x8 Qf[2][2][2];
#pragma unroll
    for (int b = 0; b < 2; b++)
#pragma unroll
        for (int mt = 0; mt < 2; mt++)
#pragma unroll
            for (int hc = 0; hc < 2; hc++)
                Qf[b][mt][hc] = *(const bf16x8*)(qn +
                    ((size_t)(qtv * 2 + b) * NT + qrow0 + wstrip + mt * 16 + l15) * 64 +
                    hc * 32 + quad * 8);

    f32x4 acc2[2][4][2];   // [b][ht][mt]  (acc^T: row=h, col=query)
#pragma unroll
    for (int b = 0; b < 2; b++)
#pragma unroll
        for (int ht = 0; ht < 4; ht++)
#pragma unroll
            for (int mt = 0; mt < 2; mt++) {
                f32x4 z = {0.f, 0.f, 0.f, 0.f};
                acc2[b][ht][mt] = z;
            }
    float rsl[2] = {0.f, 0.f};

    // ---- preload staging + mask regs for first iteration ----
    u32x4 kreg[4], vreg[4];
#pragma unroll
    for (int i = 0; i < 4; i++) {
        kreg[i] = *(const u32x4*)(kn + ((size_t)(e * 2 + s_b[i]) * NT + jbeg + s_jl[i]) * 64 + s_ch[i] * 8);
        vreg[i] = *(const u32x4*)(vT + ((size_t)(pv * 2 + s_b[i]) * 64 + s_jl[i]) * NT + jbeg + s_ch[i] * 8);
    }
    f32x4 mv[2][4];
#pragma unroll
    for (int mt = 0; mt < 2; mt++)
#pragma unroll
        for (int jt = 0; jt < 4; jt++)
            mv[mt][jt] = ldnt4(mask +
                (size_t)(qrow0 + wstrip + mt * 16 + l15) * NT + jbeg + jt * 16 + quad * 4);

#pragma unroll 1
    for (int ji = 0; ji < NI; ji++) {
        const int jn = (ji + 1 < NI) ? (jbeg + (ji + 1) * 64) : jbeg;   // next (clamped)

        __syncthreads();                           // prior compute done reading LDS
#pragma unroll
        for (int i = 0; i < 4; i++) {
            *(u32x4*)(&Klds[s_b[i]][s_jl[i]][s_ch[i] * 8]) = kreg[i];
            *(u32x4*)(&Vlds[s_b[i]][s_jl[i]][s_ch[i] * 8]) = vreg[i];
        }
        __syncthreads();                           // staged tile visible

        // issue next iteration's staging loads — in flight during compute
#pragma unroll
        for (int i = 0; i < 4; i++) {
            kreg[i] = *(const u32x4*)(kn + ((size_t)(e * 2 + s_b[i]) * NT + jn + s_jl[i]) * 64 + s_ch[i] * 8);
            vreg[i] = *(const u32x4*)(vT + ((size_t)(pv * 2 + s_b[i]) * 64 + s_jl[i]) * NT + jn + s_ch[i] * 8);
        }

        // mask rowsums (current mv)
#pragma unroll
        for (int mt = 0; mt < 2; mt++)
#pragma unroll
            for (int jt = 0; jt < 4; jt++)
                rsl[mt] += mv[mt][jt][0] + mv[mt][jt][1] + mv[mt][jt][2] + mv[mt][jt][3];

        // stage 1 for BOTH batches: S^T tiles, mask, pack bf16 pairs
        uint Pd[2][4][2][2];    // [b][jt][mt][d]
#pragma unroll
        for (int jt = 0; jt < 4; jt++)
#pragma unroll
            for (int b = 0; b < 2; b++) {
                bf16x8 aK0 = *(const bf16x8*)(&Klds[b][jt * 16 + l15][quad * 8]);
                bf16x8 aK1 = *(const bf16x8*)(&Klds[b][jt * 16 + l15][32 + quad * 8]);
#pragma unroll
                for (int mt = 0; mt < 2; mt++) {
                    f32x4 sc = {0.f, 0.f, 0.f, 0.f};
                    sc = __builtin_amdgcn_mfma_f32_16x16x32_bf16(aK0, Qf[b][mt][0], sc, 0, 0, 0);
                    sc = __builtin_amdgcn_mfma_f32_16x16x32_bf16(aK1, Qf[b][mt][1], sc, 0, 0, 0);
                    sc[0] *= mv[mt][jt][0]; sc[1] *= mv[mt][jt][1];
                    sc[2] *= mv[mt][jt][2]; sc[3] *= mv[mt][jt][3];
                    Pd[b][jt][mt][0] = pack2(sc[0], sc[1]);
                    Pd[b][jt][mt][1] = pack2(sc[2], sc[3]);
                }
            }

        // mv's last use is above — issue next iteration's mask loads now (nt)
#pragma unroll
        for (int mt = 0; mt < 2; mt++)
#pragma unroll
            for (int jt = 0; jt < 4; jt++)
                mv[mt][jt] = ldnt4(mask +
                    (size_t)(qrow0 + wstrip + mt * 16 + l15) * NT + jn + jt * 16 + quad * 4);

        // stage 2 per batch: B-frags via permlane row-swaps, then acc^T += VT·P^T
#pragma unroll
        for (int b = 0; b < 2; b++) {
            uint Bf[2][2][4];    // [mt][c][v]
#pragma unroll
            for (int mt = 0; mt < 2; mt++)
#pragma unroll
                for (int c = 0; c < 2; c++)
#pragma unroll
                    for (int d = 0; d < 2; d++) {
                        uint x = Pd[b][2 * c][mt][d];
                        uint y = Pd[b][2 * c + 1][mt][d];
                        asm("v_permlane32_swap_b32 %0, %1\n\t"
                            "v_permlane16_swap_b32 %0, %1"
                            : "+v"(x), "+v"(y));
                        Bf[mt][c][d]     = x;   // v = d
                        Bf[mt][c][d + 2] = y;   // v = d+2
                    }
#pragma unroll
            for (int ht = 0; ht < 4; ht++)
#pragma unroll
                for (int c = 0; c < 2; c++) {
                    bf16x8 a = *(const bf16x8*)(&Vlds[b][ht * 16 + l15][c * 32 + quad * 8]);
#pragma unroll
                    for (int mt = 0; mt < 2; mt++) {
                        u32x4 t = {Bf[mt][c][0], Bf[mt][c][1], Bf[mt][c][2], Bf[mt][c][3]};
                        bf16x8 bbv = __builtin_bit_cast(bf16x8, t);
                        acc2[b][ht][mt] =
                            __builtin_amdgcn_mfma_f32_16x16x32_bf16(a, bbv, acc2[b][ht][mt], 0, 0, 0);
                    }
                }
        }
    }

    // bf16 partial store: Pacc[chunk][e][b][n][h], one u16x4 (8B) per frag
#pragma unroll
    for (int b = 0; b < 2; b++)
#pragma unroll
        for (int ht = 0; ht < 4; ht++)
#pragma unroll
            for (int mt = 0; mt < 2; mt++) {
                const int n = qrow0 + wstrip + mt * 16 + l15;
                u16x4 pk;
#pragma unroll
                for (int r2 = 0; r2 < 4; r2++)
                    pk[r2] = __builtin_bit_cast(unsigned short, (bf16)acc2[b][ht][mt][r2]);
                *(u16x4*)(Pacc + ((((size_t)(jcv * 6 + e) * 2 + b) * NT + n) << 6) +
                          ht * 16 + quad * 4) = pk;
            }
    // mask rowsums: quads hold disjoint j segments
#pragma unroll
    for (int mt = 0; mt < 2; mt++) {
        float v = rsl[mt];
        v += __shfl_xor(v, 16);
        v += __shfl_xor(v, 32);
        if (quad == 0)
            rsO[(size_t)(jcv * 6 + e) * NT + qrow0 + wstrip + mt * 16 + l15] = v;
    }
}

// ---------------------------------------------------------------------------
// Kernel 3: combine bf16 partials over JC chunks in fp32 (acc_t = ΣP/Σrs),
// dt_t = 2*sigmoid(h_t Wdt_t^T + b) - 1, h_tn = h_t + step*dt*u_t, outputs.
// Pacc bf16 [chunk][e][b][n][h]: bf16x8 loads. rs summed over chunks.
// Output columns split across 2 blocks (ih), grid 768.
// ---------------------------------------------------------------------------
template<int JC>
__global__ __launch_bounds__(256) void update_kernel(
    const float* __restrict__ x0, const float* __restrict__ h0,
    const float* __restrict__ h1, const float* __restrict__ h2,
    const float* __restrict__ Wsu0, const float* __restrict__ Wsu12,
    const float* __restrict__ Wdt, const float* __restrict__ bdt,
    const float* __restrict__ stepp, const float* __restrict__ oscp,
    const bf16* __restrict__ Pacc, const float* __restrict__ rs,
    float* __restrict__ dout)
{
    const int tid = threadIdx.x, wid = tid >> 6, lane = tid & 63;
    const int l15 = lane & 15, quad = lane >> 4;
    const int bx = blockIdx.x;
    const int ih = (bx >= 384) ? 1 : 0;          // column half: it = ih*2 + ii
    const int base = bx - ih * 384;              // 0..383
    const int rt = base & 127, t = base >> 7;
    const int g0 = rt * 64;
    const int grow = g0 + wid * 16 + l15;
    const int n = grow & 4095, bb = grow >> 12;
    const float step = *stepp, osc = *oscp;
    const float* hs[3] = {h0, h1, h2};
    const float* __restrict__ ht_base = hs[t];

    bf16x8 afh[2], afacc[2], afx;
#pragma unroll
    for (int hc = 0; hc < 2; hc++)
        afh[hc] = ld8f(ht_base + (size_t)grow * 64 + hc * 32 + quad * 8);
    if (t == 0) afx = ld8f(x0 + (size_t)grow * 32 + quad * 8);

    float s0 = 0.f, s1 = 0.f;
#pragma unroll
    for (int jc = 0; jc < JC; jc++) {
        s0 += rs[(size_t)(jc * 6 + 2 * t) * NT + n];
        s1 += rs[(size_t)(jc * 6 + 2 * t + 1) * NT + n];
    }
    const float i0 = 1.f / s0, i1 = 1.f / s1;
#pragma unroll
    for (int hc = 0; hc < 2; hc++) {
        float S0[8] = {0,0,0,0,0,0,0,0}, S1[8] = {0,0,0,0,0,0,0,0};
#pragma unroll
        for (int jc = 0; jc < JC; jc++) {
            const bf16* p0 = Pacc + ((((size_t)(jc * 6 + 2 * t) * 2 + bb) * NT + n) << 6) +
                             hc * 32 + quad * 8;
            const bf16* p1 = Pacc + ((((size_t)(jc * 6 + 2 * t + 1) * 2 + bb) * NT + n) << 6) +
                             hc * 32 + quad * 8;
            bf16x8 v0 = *(const bf16x8*)p0;
            bf16x8 v1 = *(const bf16x8*)p1;
#pragma unroll
            for (int j = 0; j < 8; j++) { S0[j] += (float)v0[j]; S1[j] += (float)v1[j]; }
        }
        bf16x8 v;
#pragma unroll
        for (int j = 0; j < 8; j++) v[j] = (bf16)(S0[j] * i0 + S1[j] * i1);
        afacc[hc] = v;
    }

#pragma unroll
    for (int ii = 0; ii < 2; ii++) {
        const int it = ih * 2 + ii;
        const float bdtv = bdt[t * 64 + it * 16 + l15];
        f32x4 z = {0.f, 0.f, 0.f, 0.f};
        f32x4 u = {0.f, 0.f, 0.f, 0.f};
#pragma unroll
        for (int hc = 0; hc < 2; hc++) {
            bf16x8 wb = ld8f(Wdt + (size_t)t * 4096 + (size_t)(it * 16 + l15) * 64 + hc * 32 + quad * 8);
            z = __builtin_amdgcn_mfma_f32_16x16x32_bf16(afh[hc], wb, z, 0, 0, 0);
        }
        if (t == 0) {
            bf16x8 w0 = ld8f(Wsu0 + (size_t)(it * 16 + l15) * 96 + quad * 8);
            u = __builtin_amdgcn_mfma_f32_16x16x32_bf16(afx, w0, u, 0, 0, 0);
#pragma unroll
            for (int kc = 0; kc < 2; kc++) {
                bf16x8 wk = ld8f(Wsu0 + (size_t)(it * 16 + l15) * 96 + 32 + kc * 32 + quad * 8);
                u = __builtin_amdgcn_mfma_f32_16x16x32_bf16(afacc[kc], wk, u, 0, 0, 0);
            }
        } else {
#pragma unroll
            for (int kc = 0; kc < 2; kc++) {
                bf16x8 wk = ld8f(Wsu12 + (size_t)(t - 1) * 4096 + (size_t)(it * 16 + l15) * 64 + kc * 32 + quad * 8);
                u = __builtin_amdgcn_mfma_f32_16x16x32_bf16(afacc[kc], wk, u, 0, 0, 0);
            }
        }
        const int colg = it * 16 + l15;
#pragma unroll
        for (int r = 0; r < 4; r++) {
            int row = g0 + wid * 16 + quad * 4 + r;
            float zz = z[r] + bdtv;
            float dtv = 2.f / (1.f + __expf(-zz)) - 1.f;
            float hval = ht_base[(size_t)row * 64 + colg];
            float hn = hval + step * dtv * u[r];
            dout[65536 + (size_t)t * 524288 + (size_t)row * 64 + colg] = hn;
            if (t == 2 && colg < 8)
                dout[(size_t)row * 8 + colg] = osc * hn;
        }
    }
}

extern "C" void kernel_launch(void* const* d_in, const int* in_sizes, int n_in,
                              void* d_out, int out_size, void* d_ws, size_t ws_size,
                              hipStream_t stream) {
    const float* x0   = (const float*)d_in[0];
    const float* h0   = (const float*)d_in[1];
    const float* h1   = (const float*)d_in[2];
    const float* h2   = (const float*)d_in[3];
    const float* m00  = (const float*)d_in[4];
    const float* m20  = (const float*)d_in[5];
    const float* m01  = (const float*)d_in[6];
    const float* m11  = (const float*)d_in[7];
    const float* m12  = (const float*)d_in[8];
    const float* m22  = (const float*)d_in[9];
    const float* Wq   = (const float*)d_in[10];
    const float* Wk   = (const float*)d_in[11];
    const float* Wsu0 = (const float*)d_in[12];
    const float* Wsu12= (const float*)d_in[13];
    const float* Wdt  = (const float*)d_in[14];
    const float* bdt  = (const float*)d_in[15];
    const float* step = (const float*)d_in[16];
    const float* oscl = (const float*)d_in[17];

    // workspace layout (element counts)
    bf16* qn  = (bf16*)d_ws;                    // 3*2*4096*64 = 1,572,864
    bf16* kn  = qn + 1572864;                   // 6*2*4096*64 = 3,145,728
    bf16* vT  = kn + 3145728;                   // 3*2*64*4096 = 1,572,864
    float* rs = (float*)(vT + 1572864);         // JC*6*4096 floats
    // Pacc (bf16) follows rs: JC*6*2*4096*64 bf16 [chunk][e][b][n][h]

    // bytes: 12,582,912 fixed + JC*98,304 (rs) + JC*6,291,456 (Pacc bf16)
    auto need = [](size_t jc) { return 12582912 + jc * 98304 + jc * 6291456; };
    const int JC = (ws_size >= need(8)) ? 8
                 : ((ws_size >= need(4)) ? 4 : ((ws_size >= need(2)) ? 2 : 1));
    bf16* Pacc = (bf16*)(rs + (size_t)JC * 24576);

    prep_kernel<<<1536, 256, 0, stream>>>(h0, h1, h2, Wq, Wk, qn, kn, vT);

    if (JC == 8) {
        attn_kernel<8><<<6 * 32 * 8, 256, 0, stream>>>(qn, kn, vT, m00, m20, m01, m11, m12, m22, Pacc, rs);
        update_kernel<8><<<768, 256, 0, stream>>>(x0, h0, h1, h2, Wsu0, Wsu12, Wdt, bdt,
                                                  step, oscl, Pacc, rs, (float*)d_out);
    } else if (JC == 4) {
        attn_kernel<4><<<6 * 32 * 4, 256, 0, stream>>>(qn, kn, vT, m00, m20, m01, m11, m12, m22, Pacc, rs);
        update_kernel<4><<<768, 256, 0, stream>>>(x0, h0, h1, h2, Wsu0, Wsu12, Wdt, bdt,
                                                  step, oscl, Pacc, rs, (float*)d_out);
    } else if (JC == 2) {
        attn_kernel<2><<<6 * 32 * 2, 256, 0, stream>>>(qn, kn, vT, m00, m20, m01, m11, m12, m22, Pacc, rs);
        update_kernel<2><<<768, 256, 0, stream>>>(x0, h0, h1, h2, Wsu0, Wsu12, Wdt, bdt,
                                                  step, oscl, Pacc, rs, (float*)d_out);
    } else {
        attn_kernel<1><<<6 * 32 * 1, 256, 0, stream>>>(qn, kn, vT, m00, m20, m01, m11, m12, m22, Pacc, rs);
        update_kernel<1><<<768, 256, 0, stream>>>(x0, h0, h1, h2, Wsu0, Wsu12, Wdt, bdt,
                                                  step, oscl, Pacc, rs, (float*)d_out);
    }
}

// Round 12
// 465.164 us; speedup vs baseline: 1.0215x; 1.0215x over previous
//
#include <hip/hip_runtime.h>

typedef __bf16 bf16;
typedef bf16 bf16x8 __attribute__((ext_vector_type(8)));
typedef float f32x4 __attribute__((ext_vector_type(4)));
typedef unsigned int uint;
typedef uint u32x4 __attribute__((ext_vector_type(4)));
typedef unsigned short u16x4 __attribute__((ext_vector_type(4)));
typedef unsigned short u16x8 __attribute__((ext_vector_type(8)));

constexpr int NT = 4096;   // sequence length N
// H = 64, B = 2

__device__ __forceinline__ bf16x8 ld8f(const float* p) {
    f32x4 a = *(const f32x4*)p;
    f32x4 b = *(const f32x4*)(p + 4);
    bf16x8 v;
    v[0] = (bf16)a[0]; v[1] = (bf16)a[1]; v[2] = (bf16)a[2]; v[3] = (bf16)a[3];
    v[4] = (bf16)b[0]; v[5] = (bf16)b[1]; v[6] = (bf16)b[2]; v[7] = (bf16)b[3];
    return v;
}

__device__ __forceinline__ uint pack2(float a, float b) {
    unsigned short ua = __builtin_bit_cast(unsigned short, (bf16)a);
    unsigned short ub = __builtin_bit_cast(unsigned short, (bf16)b);
    return (uint)ua | ((uint)ub << 16);
}

// non-temporal f32x4 load: masks are a 402MB single-use stream — bypass
// L3 retention (nt) so the stream doesn't churn Infinity Cache.
__device__ __forceinline__ f32x4 ldnt4(const float* p) {
    return __builtin_nontemporal_load((const f32x4*)p);
}

// ---------------------------------------------------------------------------
// Kernel 1: grid = 1536. slices 0..8: one projection each (q0,q1,q2,k0..k5);
// slices 9..11: bf16 transpose vT for one pred each.
// ---------------------------------------------------------------------------
__global__ __launch_bounds__(256) void prep_kernel(
    const float* __restrict__ h0, const float* __restrict__ h1, const float* __restrict__ h2,
    const float* __restrict__ Wq, const float* __restrict__ Wk,
    bf16* __restrict__ qn, bf16* __restrict__ kn, bf16* __restrict__ vT)
{
    __shared__ __align__(16) unsigned short tlds[4][16][72];
    const int tid = threadIdx.x, wid = tid >> 6, lane = tid & 63;
    const int l15 = lane & 15, quad = lane >> 4;
    const int bx = blockIdx.x;
    const int rt = bx & 127, sl = bx >> 7;       // slice 0..11
    const int g0 = rt * 64;
    const int grow = g0 + wid * 16 + l15;        // A-frag row (global b*N+n)
    const float* hs[3] = {h0, h1, h2};
    const int predmap[6] = {0, 2, 0, 1, 1, 2};

    if (sl >= 9) {
        // ---- transpose slice: vT[p][b][h][n] ----
        const int p = sl - 9;
        bf16x8 af[2];
#pragma unroll
        for (int hc = 0; hc < 2; hc++)
            af[hc] = ld8f(hs[p] + (size_t)grow * 64 + hc * 32 + quad * 8);
#pragma unroll
        for (int hc = 0; hc < 2; hc++)
            *(u16x8*)(&tlds[wid][l15][hc * 32 + quad * 8]) = __builtin_bit_cast(u16x8, af[hc]);
        unsigned short vals[16];
#pragma unroll
        for (int r = 0; r < 16; r++) vals[r] = tlds[wid][r][lane];
        uint us[8];
#pragma unroll
        for (int k = 0; k < 8; k++) us[k] = (uint)vals[2 * k] | ((uint)vals[2 * k + 1] << 16);
        const int gr0 = g0 + wid * 16;
        const int bb = gr0 >> 12, n0 = gr0 & 4095;
        uint* dst = (uint*)(vT + ((size_t)(p * 2 + bb) * 64 + lane) * NT + n0);
        u32x4 w0 = {us[0], us[1], us[2], us[3]};
        u32x4 w1 = {us[4], us[5], us[6], us[7]};
        *(u32x4*)dst = w0;
        *(u32x4*)(dst + 4) = w1;
        return;
    }

    // ---- projection slice ----
    const int pj = sl;
    const float* W = (pj < 3) ? (Wq + pj * 4096) : (Wk + (pj - 3) * 4096);
    const int src = (pj < 3) ? pj : predmap[pj - 3];
    bf16* outp = (pj < 3) ? (qn + (size_t)pj * 2 * NT * 64)
                          : (kn + (size_t)(pj - 3) * 2 * NT * 64);
    bf16x8 af[2];
#pragma unroll
    for (int hc = 0; hc < 2; hc++)
        af[hc] = ld8f(hs[src] + (size_t)grow * 64 + hc * 32 + quad * 8);

    f32x4 s[4];
#pragma unroll
    for (int it = 0; it < 4; it++) {
        f32x4 acc = {0.f, 0.f, 0.f, 0.f};
#pragma unroll
        for (int hc = 0; hc < 2; hc++) {
            bf16x8 wb = ld8f(W + (size_t)(it * 16 + l15) * 64 + hc * 32 + quad * 8);
            acc = __builtin_amdgcn_mfma_f32_16x16x32_bf16(af[hc], wb, acc, 0, 0, 0);
        }
        s[it] = acc;
    }
#pragma unroll
    for (int r = 0; r < 4; r++) {
        float ss = s[0][r] * s[0][r] + s[1][r] * s[1][r] + s[2][r] * s[2][r] + s[3][r] * s[3][r];
        ss += __shfl_xor(ss, 1); ss += __shfl_xor(ss, 2);
        ss += __shfl_xor(ss, 4); ss += __shfl_xor(ss, 8);
        float rn = rsqrtf(ss);
        s[0][r] *= rn; s[1][r] *= rn; s[2][r] *= rn; s[3][r] *= rn;
    }
    const int rowbase = g0 + wid * 16 + quad * 4;
#pragma unroll
    for (int it = 0; it < 4; it++)
#pragma unroll
        for (int r = 0; r < 4; r++)
            outp[(size_t)(rowbase + r) * 64 + it * 16 + l15] = (bf16)s[it][r];
}

// ---------------------------------------------------------------------------
// Kernel 2: masked cosine attention — best-measured configuration (R10):
// fused NT fp32 masks, single mask-register set (loads issued right after
// last use), single LDS buffer, 2 barriers, register-prefetched K/V staging,
// permlane B-frag exchange, bf16 Pacc, in-kernel rowsums. VGPR 84 ->
// 3 blocks/CU. JC=4 (JC=8 measured worse: doubled Pacc traffic, no
// occupancy gain). grid = 6 edges * 32 q-tiles(128 rows) * JC.
// ---------------------------------------------------------------------------
template<int JC>
__global__ __launch_bounds__(256, 3) void attn_kernel(
    const bf16* __restrict__ qn, const bf16* __restrict__ kn, const bf16* __restrict__ vT,
    const float* __restrict__ m00, const float* __restrict__ m20, const float* __restrict__ m01,
    const float* __restrict__ m11, const float* __restrict__ m12, const float* __restrict__ m22,
    bf16* __restrict__ Pacc, float* __restrict__ rsO)
{
    __shared__ __align__(16) bf16 Klds[2][64][72];
    __shared__ __align__(16) bf16 Vlds[2][64][72];
    const int tid = threadIdx.x, wid = tid >> 6, lane = tid & 63;
    const int l15 = lane & 15, quad = lane >> 4;
    const int bx = blockIdx.x;
    const int e = bx / (32 * JC);
    const int rem = bx % (32 * JC);
    const int qt = rem / JC, jcv = rem % JC;
    const int qrow0 = qt * 128, wstrip = wid * 32;
    const int qtypemap[6] = {0, 0, 1, 1, 2, 2};
    const int predmap[6]  = {0, 2, 0, 1, 1, 2};
    const float* masks[6] = {m00, m20, m01, m11, m12, m22};
    const float* __restrict__ mask = masks[e];
    const int qtv = qtypemap[e], pv = predmap[e];
    constexpr int JSPAN = NT / JC;
    constexpr int NI = JSPAN / 64;
    const int jbeg = jcv * JSPAN;

    // per-thread staging line mapping (4 K lines + 4 V lines per thread)
    int s_b[4], s_jl[4], s_ch[4];
#pragma unroll
    for (int i = 0; i < 4; i++) {
        int u = tid + 256 * i;
        s_b[i] = u >> 9; s_jl[i] = (u >> 3) & 63; s_ch[i] = u & 7;
    }

    // Q fragments (stage-1 B-operand), register resident
    bf16x8 Qf[2][2][2];
#pragma unroll
    for (int b = 0; b < 2; b++)
#pragma unroll
        for (int mt = 0; mt < 2; mt++)
#pragma unroll
            for (int hc = 0; hc < 2; hc++)
                Qf[b][mt][hc] = *(const bf16x8*)(qn +
                    ((size_t)(qtv * 2 + b) * NT + qrow0 + wstrip + mt * 16 + l15) * 64 +
                    hc * 32 + quad * 8);

    f32x4 acc2[2][4][2];   // [b][ht][mt]  (acc^T: row=h, col=query)
#pragma unroll
    for (int b = 0; b < 2; b++)
#pragma unroll
        for (int ht = 0; ht < 4; ht++)
#pragma unroll
            for (int mt = 0; mt < 2; mt++) {
                f32x4 z = {0.f, 0.f, 0.f, 0.f};
                acc2[b][ht][mt] = z;
            }
    float rsl[2] = {0.f, 0.f};

    // ---- preload staging + mask regs for first iteration ----
    u32x4 kreg[4], vreg[4];
#pragma unroll
    for (int i = 0; i < 4; i++) {
        kreg[i] = *(const u32x4*)(kn + ((size_t)(e * 2 + s_b[i]) * NT + jbeg + s_jl[i]) * 64 + s_ch[i] * 8);
        vreg[i] = *(const u32x4*)(vT + ((size_t)(pv * 2 + s_b[i]) * 64 + s_jl[i]) * NT + jbeg + s_ch[i] * 8);
    }
    f32x4 mv[2][4];
#pragma unroll
    for (int mt = 0; mt < 2; mt++)
#pragma unroll
        for (int jt = 0; jt < 4; jt++)
            mv[mt][jt] = ldnt4(mask +
                (size_t)(qrow0 + wstrip + mt * 16 + l15) * NT + jbeg + jt * 16 + quad * 4);

#pragma unroll 1
    for (int ji = 0; ji < NI; ji++) {
        const int jn = (ji + 1 < NI) ? (jbeg + (ji + 1) * 64) : jbeg;   // next (clamped)

        __syncthreads();                           // prior compute done reading LDS
#pragma unroll
        for (int i = 0; i < 4; i++) {
            *(u32x4*)(&Klds[s_b[i]][s_jl[i]][s_ch[i] * 8]) = kreg[i];
            *(u32x4*)(&Vlds[s_b[i]][s_jl[i]][s_ch[i] * 8]) = vreg[i];
        }
        __syncthreads();                           // staged tile visible

        // issue next iteration's staging loads — in flight during compute
#pragma unroll
        for (int i = 0; i < 4; i++) {
            kreg[i] = *(const u32x4*)(kn + ((size_t)(e * 2 + s_b[i]) * NT + jn + s_jl[i]) * 64 + s_ch[i] * 8);
            vreg[i] = *(const u32x4*)(vT + ((size_t)(pv * 2 + s_b[i]) * 64 + s_jl[i]) * NT + jn + s_ch[i] * 8);
        }

        // mask rowsums (current mv)
#pragma unroll
        for (int mt = 0; mt < 2; mt++)
#pragma unroll
            for (int jt = 0; jt < 4; jt++)
                rsl[mt] += mv[mt][jt][0] + mv[mt][jt][1] + mv[mt][jt][2] + mv[mt][jt][3];

        // stage 1 for BOTH batches: S^T tiles, mask, pack bf16 pairs
        uint Pd[2][4][2][2];    // [b][jt][mt][d]
#pragma unroll
        for (int jt = 0; jt < 4; jt++)
#pragma unroll
            for (int b = 0; b < 2; b++) {
                bf16x8 aK0 = *(const bf16x8*)(&Klds[b][jt * 16 + l15][quad * 8]);
                bf16x8 aK1 = *(const bf16x8*)(&Klds[b][jt * 16 + l15][32 + quad * 8]);
#pragma unroll
                for (int mt = 0; mt < 2; mt++) {
                    f32x4 sc = {0.f, 0.f, 0.f, 0.f};
                    sc = __builtin_amdgcn_mfma_f32_16x16x32_bf16(aK0, Qf[b][mt][0], sc, 0, 0, 0);
                    sc = __builtin_amdgcn_mfma_f32_16x16x32_bf16(aK1, Qf[b][mt][1], sc, 0, 0, 0);
                    sc[0] *= mv[mt][jt][0]; sc[1] *= mv[mt][jt][1];
                    sc[2] *= mv[mt][jt][2]; sc[3] *= mv[mt][jt][3];
                    Pd[b][jt][mt][0] = pack2(sc[0], sc[1]);
                    Pd[b][jt][mt][1] = pack2(sc[2], sc[3]);
                }
            }

        // mv's last use is above — issue next iteration's mask loads now (nt)
#pragma unroll
        for (int mt = 0; mt < 2; mt++)
#pragma unroll
            for (int jt = 0; jt < 4; jt++)
                mv[mt][jt] = ldnt4(mask +
                    (size_t)(qrow0 + wstrip + mt * 16 + l15) * NT + jn + jt * 16 + quad * 4);

        // stage 2 per batch: B-frags via permlane row-swaps, then acc^T += VT·P^T
#pragma unroll
        for (int b = 0; b < 2; b++) {
            uint Bf[2][2][4];    // [mt][c][v]
#pragma unroll
            for (int mt = 0; mt < 2; mt++)
#pragma unroll
                for (int c = 0; c < 2; c++)
#pragma unroll
                    for (int d = 0; d < 2; d++) {
                        uint x = Pd[b][2 * c][mt][d];
                        uint y = Pd[b][2 * c + 1][mt][d];
                        asm("v_permlane32_swap_b32 %0, %1\n\t"
                            "v_permlane16_swap_b32 %0, %1"
                            : "+v"(x), "+v"(y));
                        Bf[mt][c][d]     = x;   // v = d
                        Bf[mt][c][d + 2] = y;   // v = d+2
                    }
#pragma unroll
            for (int ht = 0; ht < 4; ht++)
#pragma unroll
                for (int c = 0; c < 2; c++) {
                    bf16x8 a = *(const bf16x8*)(&Vlds[b][ht * 16 + l15][c * 32 + quad * 8]);
#pragma unroll
                    for (int mt = 0; mt < 2; mt++) {
                        u32x4 t = {Bf[mt][c][0], Bf[mt][c][1], Bf[mt][c][2], Bf[mt][c][3]};
                        bf16x8 bbv = __builtin_bit_cast(bf16x8, t);
                        acc2[b][ht][mt] =
                            __builtin_amdgcn_mfma_f32_16x16x32_bf16(a, bbv, acc2[b][ht][mt], 0, 0, 0);
                    }
                }
        }
    }

    // bf16 partial store: Pacc[chunk][e][b][n][h], one u16x4 (8B) per frag
#pragma unroll
    for (int b = 0; b < 2; b++)
#pragma unroll
        for (int ht = 0; ht < 4; ht++)
#pragma unroll
            for (int mt = 0; mt < 2; mt++) {
                const int n = qrow0 + wstrip + mt * 16 + l15;
                u16x4 pk;
#pragma unroll
                for (int r2 = 0; r2 < 4; r2++)
                    pk[r2] = __builtin_bit_cast(unsigned short, (bf16)acc2[b][ht][mt][r2]);
                *(u16x4*)(Pacc + ((((size_t)(jcv * 6 + e) * 2 + b) * NT + n) << 6) +
                          ht * 16 + quad * 4) = pk;
            }
    // mask rowsums: quads hold disjoint j segments
#pragma unroll
    for (int mt = 0; mt < 2; mt++) {
        float v = rsl[mt];
        v += __shfl_xor(v, 16);
        v += __shfl_xor(v, 32);
        if (quad == 0)
            rsO[(size_t)(jcv * 6 + e) * NT + qrow0 + wstrip + mt * 16 + l15] = v;
    }
}

// ---------------------------------------------------------------------------
// Kernel 3: combine bf16 partials over JC chunks in fp32 (acc_t = ΣP/Σrs),
// dt_t = 2*sigmoid(h_t Wdt_t^T + b) - 1, h_tn = h_t + step*dt*u_t, outputs.
// Pacc bf16 [chunk][e][b][n][h]: bf16x8 loads. rs summed over chunks.
// Output columns split across 2 blocks (ih), grid 768.
// ---------------------------------------------------------------------------
template<int JC>
__global__ __launch_bounds__(256) void update_kernel(
    const float* __restrict__ x0, const float* __restrict__ h0,
    const float* __restrict__ h1, const float* __restrict__ h2,
    const float* __restrict__ Wsu0, const float* __restrict__ Wsu12,
    const float* __restrict__ Wdt, const float* __restrict__ bdt,
    const float* __restrict__ stepp, const float* __restrict__ oscp,
    const bf16* __restrict__ Pacc, const float* __restrict__ rs,
    float* __restrict__ dout)
{
    const int tid = threadIdx.x, wid = tid >> 6, lane = tid & 63;
    const int l15 = lane & 15, quad = lane >> 4;
    const int bx = blockIdx.x;
    const int ih = (bx >= 384) ? 1 : 0;          // column half: it = ih*2 + ii
    const int base = bx - ih * 384;              // 0..383
    const int rt = base & 127, t = base >> 7;
    const int g0 = rt * 64;
    const int grow = g0 + wid * 16 + l15;
    const int n = grow & 4095, bb = grow >> 12;
    const float step = *stepp, osc = *oscp;
    const float* hs[3] = {h0, h1, h2};
    const float* __restrict__ ht_base = hs[t];

    bf16x8 afh[2], afacc[2], afx;
#pragma unroll
    for (int hc = 0; hc < 2; hc++)
        afh[hc] = ld8f(ht_base + (size_t)grow * 64 + hc * 32 + quad * 8);
    if (t == 0) afx = ld8f(x0 + (size_t)grow * 32 + quad * 8);

    float s0 = 0.f, s1 = 0.f;
#pragma unroll
    for (int jc = 0; jc < JC; jc++) {
        s0 += rs[(size_t)(jc * 6 + 2 * t) * NT + n];
        s1 += rs[(size_t)(jc * 6 + 2 * t + 1) * NT + n];
    }
    const float i0 = 1.f / s0, i1 = 1.f / s1;
#pragma unroll
    for (int hc = 0; hc < 2; hc++) {
        float S0[8] = {0,0,0,0,0,0,0,0}, S1[8] = {0,0,0,0,0,0,0,0};
#pragma unroll
        for (int jc = 0; jc < JC; jc++) {
            const bf16* p0 = Pacc + ((((size_t)(jc * 6 + 2 * t) * 2 + bb) * NT + n) << 6) +
                             hc * 32 + quad * 8;
            const bf16* p1 = Pacc + ((((size_t)(jc * 6 + 2 * t + 1) * 2 + bb) * NT + n) << 6) +
                             hc * 32 + quad * 8;
            bf16x8 v0 = *(const bf16x8*)p0;
            bf16x8 v1 = *(const bf16x8*)p1;
#pragma unroll
            for (int j = 0; j < 8; j++) { S0[j] += (float)v0[j]; S1[j] += (float)v1[j]; }
        }
        bf16x8 v;
#pragma unroll
        for (int j = 0; j < 8; j++) v[j] = (bf16)(S0[j] * i0 + S1[j] * i1);
        afacc[hc] = v;
    }

#pragma unroll
    for (int ii = 0; ii < 2; ii++) {
        const int it = ih * 2 + ii;
        const float bdtv = bdt[t * 64 + it * 16 + l15];
        f32x4 z = {0.f, 0.f, 0.f, 0.f};
        f32x4 u = {0.f, 0.f, 0.f, 0.f};
#pragma unroll
        for (int hc = 0; hc < 2; hc++) {
            bf16x8 wb = ld8f(Wdt + (size_t)t * 4096 + (size_t)(it * 16 + l15) * 64 + hc * 32 + quad * 8);
            z = __builtin_amdgcn_mfma_f32_16x16x32_bf16(afh[hc], wb, z, 0, 0, 0);
        }
        if (t == 0) {
            bf16x8 w0 = ld8f(Wsu0 + (size_t)(it * 16 + l15) * 96 + quad * 8);
            u = __builtin_amdgcn_mfma_f32_16x16x32_bf16(afx, w0, u, 0, 0, 0);
#pragma unroll
            for (int kc = 0; kc < 2; kc++) {
                bf16x8 wk = ld8f(Wsu0 + (size_t)(it * 16 + l15) * 96 + 32 + kc * 32 + quad * 8);
                u = __builtin_amdgcn_mfma_f32_16x16x32_bf16(afacc[kc], wk, u, 0, 0, 0);
            }
        } else {
#pragma unroll
            for (int kc = 0; kc < 2; kc++) {
                bf16x8 wk = ld8f(Wsu12 + (size_t)(t - 1) * 4096 + (size_t)(it * 16 + l15) * 64 + kc * 32 + quad * 8);
                u = __builtin_amdgcn_mfma_f32_16x16x32_bf16(afacc[kc], wk, u, 0, 0, 0);
            }
        }
        const int colg = it * 16 + l15;
#pragma unroll
        for (int r = 0; r < 4; r++) {
            int row = g0 + wid * 16 + quad * 4 + r;
            float zz = z[r] + bdtv;
            float dtv = 2.f / (1.f + __expf(-zz)) - 1.f;
            float hval = ht_base[(size_t)row * 64 + colg];
            float hn = hval + step * dtv * u[r];
            dout[65536 + (size_t)t * 524288 + (size_t)row * 64 + colg] = hn;
            if (t == 2 && colg < 8)
                dout[(size_t)row * 8 + colg] = osc * hn;
        }
    }
}

extern "C" void kernel_launch(void* const* d_in, const int* in_sizes, int n_in,
                              void* d_out, int out_size, void* d_ws, size_t ws_size,
                              hipStream_t stream) {
    const float* x0   = (const float*)d_in[0];
    const float* h0   = (const float*)d_in[1];
    const float* h1   = (const float*)d_in[2];
    const float* h2   = (const float*)d_in[3];
    const float* m00  = (const float*)d_in[4];
    const float* m20  = (const float*)d_in[5];
    const float* m01  = (const float*)d_in[6];
    const float* m11  = (const float*)d_in[7];
    const float* m12  = (const float*)d_in[8];
    const float* m22  = (const float*)d_in[9];
    const float* Wq   = (const float*)d_in[10];
    const float* Wk   = (const float*)d_in[11];
    const float* Wsu0 = (const float*)d_in[12];
    const float* Wsu12= (const float*)d_in[13];
    const float* Wdt  = (const float*)d_in[14];
    const float* bdt  = (const float*)d_in[15];
    const float* step = (const float*)d_in[16];
    const float* oscl = (const float*)d_in[17];

    // workspace layout (element counts)
    bf16* qn  = (bf16*)d_ws;                    // 3*2*4096*64 = 1,572,864
    bf16* kn  = qn + 1572864;                   // 6*2*4096*64 = 3,145,728
    bf16* vT  = kn + 3145728;                   // 3*2*64*4096 = 1,572,864
    float* rs = (float*)(vT + 1572864);         // JC*6*4096 floats
    // Pacc (bf16) follows rs: JC*6*2*4096*64 bf16 [chunk][e][b][n][h]

    // bytes: 12,582,912 fixed + JC*98,304 (rs) + JC*6,291,456 (Pacc bf16)
    auto need = [](size_t jc) { return 12582912 + jc * 98304 + jc * 6291456; };
    const int JC = (ws_size >= need(4)) ? 4 : ((ws_size >= need(2)) ? 2 : 1);
    bf16* Pacc = (bf16*)(rs + (size_t)JC * 24576);

    prep_kernel<<<1536, 256, 0, stream>>>(h0, h1, h2, Wq, Wk, qn, kn, vT);

    if (JC == 4) {
        attn_kernel<4><<<6 * 32 * 4, 256, 0, stream>>>(qn, kn, vT, m00, m20, m01, m11, m12, m22, Pacc, rs);
        update_kernel<4><<<768, 256, 0, stream>>>(x0, h0, h1, h2, Wsu0, Wsu12, Wdt, bdt,
                                                  step, oscl, Pacc, rs, (float*)d_out);
    } else if (JC == 2) {
        attn_kernel<2><<<6 * 32 * 2, 256, 0, stream>>>(qn, kn, vT, m00, m20, m01, m11, m12, m22, Pacc, rs);
        update_kernel<2><<<768, 256, 0, stream>>>(x0, h0, h1, h2, Wsu0, Wsu12, Wdt, bdt,
                                                  step, oscl, Pacc, rs, (float*)d_out);
    } else {
        attn_kernel<1><<<6 * 32 * 1, 256, 0, stream>>>(qn, kn, vT, m00, m20, m01, m11, m12, m22, Pacc, rs);
        update_kernel<1><<<768, 256, 0, stream>>>(x0, h0, h1, h2, Wsu0, Wsu12, Wdt, bdt,
                                                  step, oscl, Pacc, rs, (float*)d_out);
    }
}

// Round 13
// 453.470 us; speedup vs baseline: 1.0479x; 1.0258x over previous
//
#include <hip/hip_runtime.h>

typedef __bf16 bf16;
typedef bf16 bf16x8 __attribute__((ext_vector_type(8)));
typedef float f32x4 __attribute__((ext_vector_type(4)));
typedef unsigned int uint;
typedef uint u32x4 __attribute__((ext_vector_type(4)));
typedef unsigned short u16x4 __attribute__((ext_vector_type(4)));
typedef unsigned short u16x8 __attribute__((ext_vector_type(8)));

constexpr int NT = 4096;   // sequence length N
// H = 64, B = 2

__device__ __forceinline__ bf16x8 ld8f(const float* p) {
    f32x4 a = *(const f32x4*)p;
    f32x4 b = *(const f32x4*)(p + 4);
    bf16x8 v;
    v[0] = (bf16)a[0]; v[1] = (bf16)a[1]; v[2] = (bf16)a[2]; v[3] = (bf16)a[3];
    v[4] = (bf16)b[0]; v[5] = (bf16)b[1]; v[6] = (bf16)b[2]; v[7] = (bf16)b[3];
    return v;
}

__device__ __forceinline__ uint pack2(float a, float b) {
    unsigned short ua = __builtin_bit_cast(unsigned short, (bf16)a);
    unsigned short ub = __builtin_bit_cast(unsigned short, (bf16)b);
    return (uint)ua | ((uint)ub << 16);
}

// ---------------------------------------------------------------------------
// Kernel 1: grid = 1536. slices 0..8: one projection each (q0,q1,q2,k0..k5);
// slices 9..11: bf16 transpose vT for one pred each.
// ---------------------------------------------------------------------------
__global__ __launch_bounds__(256) void prep_kernel(
    const float* __restrict__ h0, const float* __restrict__ h1, const float* __restrict__ h2,
    const float* __restrict__ Wq, const float* __restrict__ Wk,
    bf16* __restrict__ qn, bf16* __restrict__ kn, bf16* __restrict__ vT)
{
    __shared__ __align__(16) unsigned short tlds[4][16][72];
    const int tid = threadIdx.x, wid = tid >> 6, lane = tid & 63;
    const int l15 = lane & 15, quad = lane >> 4;
    const int bx = blockIdx.x;
    const int rt = bx & 127, sl = bx >> 7;       // slice 0..11
    const int g0 = rt * 64;
    const int grow = g0 + wid * 16 + l15;        // A-frag row (global b*N+n)
    const float* hs[3] = {h0, h1, h2};
    const int predmap[6] = {0, 2, 0, 1, 1, 2};

    if (sl >= 9) {
        // ---- transpose slice: vT[p][b][h][n] ----
        const int p = sl - 9;
        bf16x8 af[2];
#pragma unroll
        for (int hc = 0; hc < 2; hc++)
            af[hc] = ld8f(hs[p] + (size_t)grow * 64 + hc * 32 + quad * 8);
#pragma unroll
        for (int hc = 0; hc < 2; hc++)
            *(u16x8*)(&tlds[wid][l15][hc * 32 + quad * 8]) = __builtin_bit_cast(u16x8, af[hc]);
        unsigned short vals[16];
#pragma unroll
        for (int r = 0; r < 16; r++) vals[r] = tlds[wid][r][lane];
        uint us[8];
#pragma unroll
        for (int k = 0; k < 8; k++) us[k] = (uint)vals[2 * k] | ((uint)vals[2 * k + 1] << 16);
        const int gr0 = g0 + wid * 16;
        const int bb = gr0 >> 12, n0 = gr0 & 4095;
        uint* dst = (uint*)(vT + ((size_t)(p * 2 + bb) * 64 + lane) * NT + n0);
        u32x4 w0 = {us[0], us[1], us[2], us[3]};
        u32x4 w1 = {us[4], us[5], us[6], us[7]};
        *(u32x4*)dst = w0;
        *(u32x4*)(dst + 4) = w1;
        return;
    }

    // ---- projection slice ----
    const int pj = sl;
    const float* W = (pj < 3) ? (Wq + pj * 4096) : (Wk + (pj - 3) * 4096);
    const int src = (pj < 3) ? pj : predmap[pj - 3];
    bf16* outp = (pj < 3) ? (qn + (size_t)pj * 2 * NT * 64)
                          : (kn + (size_t)(pj - 3) * 2 * NT * 64);
    bf16x8 af[2];
#pragma unroll
    for (int hc = 0; hc < 2; hc++)
        af[hc] = ld8f(hs[src] + (size_t)grow * 64 + hc * 32 + quad * 8);

    f32x4 s[4];
#pragma unroll
    for (int it = 0; it < 4; it++) {
        f32x4 acc = {0.f, 0.f, 0.f, 0.f};
#pragma unroll
        for (int hc = 0; hc < 2; hc++) {
            bf16x8 wb = ld8f(W + (size_t)(it * 16 + l15) * 64 + hc * 32 + quad * 8);
            acc = __builtin_amdgcn_mfma_f32_16x16x32_bf16(af[hc], wb, acc, 0, 0, 0);
        }
        s[it] = acc;
    }
#pragma unroll
    for (int r = 0; r < 4; r++) {
        float ss = s[0][r] * s[0][r] + s[1][r] * s[1][r] + s[2][r] * s[2][r] + s[3][r] * s[3][r];
        ss += __shfl_xor(ss, 1); ss += __shfl_xor(ss, 2);
        ss += __shfl_xor(ss, 4); ss += __shfl_xor(ss, 8);
        float rn = rsqrtf(ss);
        s[0][r] *= rn; s[1][r] *= rn; s[2][r] *= rn; s[3][r] *= rn;
    }
    const int rowbase = g0 + wid * 16 + quad * 4;
#pragma unroll
    for (int it = 0; it < 4; it++)
#pragma unroll
        for (int r = 0; r < 4; r++)
            outp[(size_t)(rowbase + r) * 64 + it * 16 + l15] = (bf16)s[it][r];
}

// ---------------------------------------------------------------------------
// Kernel 2: masked cosine attention — best-measured configuration (R9,
// 459.7 µs total): fused fp32 masks (regular loads; NT variant measured
// equal-or-worse at total level), single mask-register set with loads
// issued right after last use (hidden under stage-2 MFMA + next stage-1),
// single LDS buffer, 2 barriers, register-prefetched K/V staging, permlane
// B-frag exchange, bf16 Pacc, in-kernel rowsums. VGPR 84 -> 3 blocks/CU.
// grid = 6 edges * 32 q-tiles(128 rows) * JC.
// ---------------------------------------------------------------------------
template<int JC>
__global__ __launch_bounds__(256, 3) void attn_kernel(
    const bf16* __restrict__ qn, const bf16* __restrict__ kn, const bf16* __restrict__ vT,
    const float* __restrict__ m00, const float* __restrict__ m20, const float* __restrict__ m01,
    const float* __restrict__ m11, const float* __restrict__ m12, const float* __restrict__ m22,
    bf16* __restrict__ Pacc, float* __restrict__ rsO)
{
    __shared__ __align__(16) bf16 Klds[2][64][72];
    __shared__ __align__(16) bf16 Vlds[2][64][72];
    const int tid = threadIdx.x, wid = tid >> 6, lane = tid & 63;
    const int l15 = lane & 15, quad = lane >> 4;
    const int bx = blockIdx.x;
    const int e = bx / (32 * JC);
    const int rem = bx % (32 * JC);
    const int qt = rem / JC, jcv = rem % JC;
    const int qrow0 = qt * 128, wstrip = wid * 32;
    const int qtypemap[6] = {0, 0, 1, 1, 2, 2};
    const int predmap[6]  = {0, 2, 0, 1, 1, 2};
    const float* masks[6] = {m00, m20, m01, m11, m12, m22};
    const float* __restrict__ mask = masks[e];
    const int qtv = qtypemap[e], pv = predmap[e];
    constexpr int JSPAN = NT / JC;
    constexpr int NI = JSPAN / 64;
    const int jbeg = jcv * JSPAN;

    // per-thread staging line mapping (4 K lines + 4 V lines per thread)
    int s_b[4], s_jl[4], s_ch[4];
#pragma unroll
    for (int i = 0; i < 4; i++) {
        int u = tid + 256 * i;
        s_b[i] = u >> 9; s_jl[i] = (u >> 3) & 63; s_ch[i] = u & 7;
    }

    // Q fragments (stage-1 B-operand), register resident
    bf16x8 Qf[2][2][2];
#pragma unroll
    for (int b = 0; b < 2; b++)
#pragma unroll
        for (int mt = 0; mt < 2; mt++)
#pragma unroll
            for (int hc = 0; hc < 2; hc++)
                Qf[b][mt][hc] = *(const bf16x8*)(qn +
                    ((size_t)(qtv * 2 + b) * NT + qrow0 + wstrip + mt * 16 + l15) * 64 +
                    hc * 32 + quad * 8);

    f32x4 acc2[2][4][2];   // [b][ht][mt]  (acc^T: row=h, col=query)
#pragma unroll
    for (int b = 0; b < 2; b++)
#pragma unroll
        for (int ht = 0; ht < 4; ht++)
#pragma unroll
            for (int mt = 0; mt < 2; mt++) {
                f32x4 z = {0.f, 0.f, 0.f, 0.f};
                acc2[b][ht][mt] = z;
            }
    float rsl[2] = {0.f, 0.f};

    // ---- preload staging + mask regs for first iteration ----
    u32x4 kreg[4], vreg[4];
#pragma unroll
    for (int i = 0; i < 4; i++) {
        kreg[i] = *(const u32x4*)(kn + ((size_t)(e * 2 + s_b[i]) * NT + jbeg + s_jl[i]) * 64 + s_ch[i] * 8);
        vreg[i] = *(const u32x4*)(vT + ((size_t)(pv * 2 + s_b[i]) * 64 + s_jl[i]) * NT + jbeg + s_ch[i] * 8);
    }
    f32x4 mv[2][4];
#pragma unroll
    for (int mt = 0; mt < 2; mt++)
#pragma unroll
        for (int jt = 0; jt < 4; jt++)
            mv[mt][jt] = *(const f32x4*)(mask +
                (size_t)(qrow0 + wstrip + mt * 16 + l15) * NT + jbeg + jt * 16 + quad * 4);

#pragma unroll 1
    for (int ji = 0; ji < NI; ji++) {
        const int jn = (ji + 1 < NI) ? (jbeg + (ji + 1) * 64) : jbeg;   // next (clamped)

        __syncthreads();                           // prior compute done reading LDS
#pragma unroll
        for (int i = 0; i < 4; i++) {
            *(u32x4*)(&Klds[s_b[i]][s_jl[i]][s_ch[i] * 8]) = kreg[i];
            *(u32x4*)(&Vlds[s_b[i]][s_jl[i]][s_ch[i] * 8]) = vreg[i];
        }
        __syncthreads();                           // staged tile visible

        // issue next iteration's staging loads — in flight during compute
#pragma unroll
        for (int i = 0; i < 4; i++) {
            kreg[i] = *(const u32x4*)(kn + ((size_t)(e * 2 + s_b[i]) * NT + jn + s_jl[i]) * 64 + s_ch[i] * 8);
            vreg[i] = *(const u32x4*)(vT + ((size_t)(pv * 2 + s_b[i]) * 64 + s_jl[i]) * NT + jn + s_ch[i] * 8);
        }

        // mask rowsums (current mv)
#pragma unroll
        for (int mt = 0; mt < 2; mt++)
#pragma unroll
            for (int jt = 0; jt < 4; jt++)
                rsl[mt] += mv[mt][jt][0] + mv[mt][jt][1] + mv[mt][jt][2] + mv[mt][jt][3];

        // stage 1 for BOTH batches: S^T tiles, mask, pack bf16 pairs
        uint Pd[2][4][2][2];    // [b][jt][mt][d]
#pragma unroll
        for (int jt = 0; jt < 4; jt++)
#pragma unroll
            for (int b = 0; b < 2; b++) {
                bf16x8 aK0 = *(const bf16x8*)(&Klds[b][jt * 16 + l15][quad * 8]);
                bf16x8 aK1 = *(const bf16x8*)(&Klds[b][jt * 16 + l15][32 + quad * 8]);
#pragma unroll
                for (int mt = 0; mt < 2; mt++) {
                    f32x4 sc = {0.f, 0.f, 0.f, 0.f};
                    sc = __builtin_amdgcn_mfma_f32_16x16x32_bf16(aK0, Qf[b][mt][0], sc, 0, 0, 0);
                    sc = __builtin_amdgcn_mfma_f32_16x16x32_bf16(aK1, Qf[b][mt][1], sc, 0, 0, 0);
                    sc[0] *= mv[mt][jt][0]; sc[1] *= mv[mt][jt][1];
                    sc[2] *= mv[mt][jt][2]; sc[3] *= mv[mt][jt][3];
                    Pd[b][jt][mt][0] = pack2(sc[0], sc[1]);
                    Pd[b][jt][mt][1] = pack2(sc[2], sc[3]);
                }
            }

        // mv's last use is above — issue next iteration's mask loads now
#pragma unroll
        for (int mt = 0; mt < 2; mt++)
#pragma unroll
            for (int jt = 0; jt < 4; jt++)
                mv[mt][jt] = *(const f32x4*)(mask +
                    (size_t)(qrow0 + wstrip + mt * 16 + l15) * NT + jn + jt * 16 + quad * 4);

        // stage 2 per batch: B-frags via permlane row-swaps, then acc^T += VT·P^T
#pragma unroll
        for (int b = 0; b < 2; b++) {
            uint Bf[2][2][4];    // [mt][c][v]
#pragma unroll
            for (int mt = 0; mt < 2; mt++)
#pragma unroll
                for (int c = 0; c < 2; c++)
#pragma unroll
                    for (int d = 0; d < 2; d++) {
                        uint x = Pd[b][2 * c][mt][d];
                        uint y = Pd[b][2 * c + 1][mt][d];
                        asm("v_permlane32_swap_b32 %0, %1\n\t"
                            "v_permlane16_swap_b32 %0, %1"
                            : "+v"(x), "+v"(y));
                        Bf[mt][c][d]     = x;   // v = d
                        Bf[mt][c][d + 2] = y;   // v = d+2
                    }
#pragma unroll
            for (int ht = 0; ht < 4; ht++)
#pragma unroll
                for (int c = 0; c < 2; c++) {
                    bf16x8 a = *(const bf16x8*)(&Vlds[b][ht * 16 + l15][c * 32 + quad * 8]);
#pragma unroll
                    for (int mt = 0; mt < 2; mt++) {
                        u32x4 t = {Bf[mt][c][0], Bf[mt][c][1], Bf[mt][c][2], Bf[mt][c][3]};
                        bf16x8 bbv = __builtin_bit_cast(bf16x8, t);
                        acc2[b][ht][mt] =
                            __builtin_amdgcn_mfma_f32_16x16x32_bf16(a, bbv, acc2[b][ht][mt], 0, 0, 0);
                    }
                }
        }
    }

    // bf16 partial store: Pacc[chunk][e][b][n][h], one u16x4 (8B) per frag
#pragma unroll
    for (int b = 0; b < 2; b++)
#pragma unroll
        for (int ht = 0; ht < 4; ht++)
#pragma unroll
            for (int mt = 0; mt < 2; mt++) {
                const int n = qrow0 + wstrip + mt * 16 + l15;
                u16x4 pk;
#pragma unroll
                for (int r2 = 0; r2 < 4; r2++)
                    pk[r2] = __builtin_bit_cast(unsigned short, (bf16)acc2[b][ht][mt][r2]);
                *(u16x4*)(Pacc + ((((size_t)(jcv * 6 + e) * 2 + b) * NT + n) << 6) +
                          ht * 16 + quad * 4) = pk;
            }
    // mask rowsums: quads hold disjoint j segments
#pragma unroll
    for (int mt = 0; mt < 2; mt++) {
        float v = rsl[mt];
        v += __shfl_xor(v, 16);
        v += __shfl_xor(v, 32);
        if (quad == 0)
            rsO[(size_t)(jcv * 6 + e) * NT + qrow0 + wstrip + mt * 16 + l15] = v;
    }
}

// ---------------------------------------------------------------------------
// Kernel 3: combine bf16 partials over JC chunks in fp32 (acc_t = ΣP/Σrs),
// dt_t = 2*sigmoid(h_t Wdt_t^T + b) - 1, h_tn = h_t + step*dt*u_t, outputs.
// Pacc bf16 [chunk][e][b][n][h]: bf16x8 loads. rs summed over chunks.
// Output columns split across 2 blocks (ih), grid 768.
// ---------------------------------------------------------------------------
template<int JC>
__global__ __launch_bounds__(256) void update_kernel(
    const float* __restrict__ x0, const float* __restrict__ h0,
    const float* __restrict__ h1, const float* __restrict__ h2,
    const float* __restrict__ Wsu0, const float* __restrict__ Wsu12,
    const float* __restrict__ Wdt, const float* __restrict__ bdt,
    const float* __restrict__ stepp, const float* __restrict__ oscp,
    const bf16* __restrict__ Pacc, const float* __restrict__ rs,
    float* __restrict__ dout)
{
    const int tid = threadIdx.x, wid = tid >> 6, lane = tid & 63;
    const int l15 = lane & 15, quad = lane >> 4;
    const int bx = blockIdx.x;
    const int ih = (bx >= 384) ? 1 : 0;          // column half: it = ih*2 + ii
    const int base = bx - ih * 384;              // 0..383
    const int rt = base & 127, t = base >> 7;
    const int g0 = rt * 64;
    const int grow = g0 + wid * 16 + l15;
    const int n = grow & 4095, bb = grow >> 12;
    const float step = *stepp, osc = *oscp;
    const float* hs[3] = {h0, h1, h2};
    const float* __restrict__ ht_base = hs[t];

    bf16x8 afh[2], afacc[2], afx;
#pragma unroll
    for (int hc = 0; hc < 2; hc++)
        afh[hc] = ld8f(ht_base + (size_t)grow * 64 + hc * 32 + quad * 8);
    if (t == 0) afx = ld8f(x0 + (size_t)grow * 32 + quad * 8);

    float s0 = 0.f, s1 = 0.f;
#pragma unroll
    for (int jc = 0; jc < JC; jc++) {
        s0 += rs[(size_t)(jc * 6 + 2 * t) * NT + n];
        s1 += rs[(size_t)(jc * 6 + 2 * t + 1) * NT + n];
    }
    const float i0 = 1.f / s0, i1 = 1.f / s1;
#pragma unroll
    for (int hc = 0; hc < 2; hc++) {
        float S0[8] = {0,0,0,0,0,0,0,0}, S1[8] = {0,0,0,0,0,0,0,0};
#pragma unroll
        for (int jc = 0; jc < JC; jc++) {
            const bf16* p0 = Pacc + ((((size_t)(jc * 6 + 2 * t) * 2 + bb) * NT + n) << 6) +
                             hc * 32 + quad * 8;
            const bf16* p1 = Pacc + ((((size_t)(jc * 6 + 2 * t + 1) * 2 + bb) * NT + n) << 6) +
                             hc * 32 + quad * 8;
            bf16x8 v0 = *(const bf16x8*)p0;
            bf16x8 v1 = *(const bf16x8*)p1;
#pragma unroll
            for (int j = 0; j < 8; j++) { S0[j] += (float)v0[j]; S1[j] += (float)v1[j]; }
        }
        bf16x8 v;
#pragma unroll
        for (int j = 0; j < 8; j++) v[j] = (bf16)(S0[j] * i0 + S1[j] * i1);
        afacc[hc] = v;
    }

#pragma unroll
    for (int ii = 0; ii < 2; ii++) {
        const int it = ih * 2 + ii;
        const float bdtv = bdt[t * 64 + it * 16 + l15];
        f32x4 z = {0.f, 0.f, 0.f, 0.f};
        f32x4 u = {0.f, 0.f, 0.f, 0.f};
#pragma unroll
        for (int hc = 0; hc < 2; hc++) {
            bf16x8 wb = ld8f(Wdt + (size_t)t * 4096 + (size_t)(it * 16 + l15) * 64 + hc * 32 + quad * 8);
            z = __builtin_amdgcn_mfma_f32_16x16x32_bf16(afh[hc], wb, z, 0, 0, 0);
        }
        if (t == 0) {
            bf16x8 w0 = ld8f(Wsu0 + (size_t)(it * 16 + l15) * 96 + quad * 8);
            u = __builtin_amdgcn_mfma_f32_16x16x32_bf16(afx, w0, u, 0, 0, 0);
#pragma unroll
            for (int kc = 0; kc < 2; kc++) {
                bf16x8 wk = ld8f(Wsu0 + (size_t)(it * 16 + l15) * 96 + 32 + kc * 32 + quad * 8);
                u = __builtin_amdgcn_mfma_f32_16x16x32_bf16(afacc[kc], wk, u, 0, 0, 0);
            }
        } else {
#pragma unroll
            for (int kc = 0; kc < 2; kc++) {
                bf16x8 wk = ld8f(Wsu12 + (size_t)(t - 1) * 4096 + (size_t)(it * 16 + l15) * 64 + kc * 32 + quad * 8);
                u = __builtin_amdgcn_mfma_f32_16x16x32_bf16(afacc[kc], wk, u, 0, 0, 0);
            }
        }
        const int colg = it * 16 + l15;
#pragma unroll
        for (int r = 0; r < 4; r++) {
            int row = g0 + wid * 16 + quad * 4 + r;
            float zz = z[r] + bdtv;
            float dtv = 2.f / (1.f + __expf(-zz)) - 1.f;
            float hval = ht_base[(size_t)row * 64 + colg];
            float hn = hval + step * dtv * u[r];
            dout[65536 + (size_t)t * 524288 + (size_t)row * 64 + colg] = hn;
            if (t == 2 && colg < 8)
                dout[(size_t)row * 8 + colg] = osc * hn;
        }
    }
}

extern "C" void kernel_launch(void* const* d_in, const int* in_sizes, int n_in,
                              void* d_out, int out_size, void* d_ws, size_t ws_size,
                              hipStream_t stream) {
    const float* x0   = (const float*)d_in[0];
    const float* h0   = (const float*)d_in[1];
    const float* h1   = (const float*)d_in[2];
    const float* h2   = (const float*)d_in[3];
    const float* m00  = (const float*)d_in[4];
    const float* m20  = (const float*)d_in[5];
    const float* m01  = (const float*)d_in[6];
    const float* m11  = (const float*)d_in[7];
    const float* m12  = (const float*)d_in[8];
    const float* m22  = (const float*)d_in[9];
    const float* Wq   = (const float*)d_in[10];
    const float* Wk   = (const float*)d_in[11];
    const float* Wsu0 = (const float*)d_in[12];
    const float* Wsu12= (const float*)d_in[13];
    const float* Wdt  = (const float*)d_in[14];
    const float* bdt  = (const float*)d_in[15];
    const float* step = (const float*)d_in[16];
    const float* oscl = (const float*)d_in[17];

    // workspace layout (element counts)
    bf16* qn  = (bf16*)d_ws;                    // 3*2*4096*64 = 1,572,864
    bf16* kn  = qn + 1572864;                   // 6*2*4096*64 = 3,145,728
    bf16* vT  = kn + 3145728;                   // 3*2*64*4096 = 1,572,864
    float* rs = (float*)(vT + 1572864);         // JC*6*4096 floats
    // Pacc (bf16) follows rs: JC*6*2*4096*64 bf16 [chunk][e][b][n][h]

    // bytes: 12,582,912 fixed + JC*98,304 (rs) + JC*6,291,456 (Pacc bf16)
    auto need = [](size_t jc) { return 12582912 + jc * 98304 + jc * 6291456; };
    const int JC = (ws_size >= need(4)) ? 4 : ((ws_size >= need(2)) ? 2 : 1);
    bf16* Pacc = (bf16*)(rs + (size_t)JC * 24576);

    prep_kernel<<<1536, 256, 0, stream>>>(h0, h1, h2, Wq, Wk, qn, kn, vT);

    if (JC == 4) {
        attn_kernel<4><<<6 * 32 * 4, 256, 0, stream>>>(qn, kn, vT, m00, m20, m01, m11, m12, m22, Pacc, rs);
        update_kernel<4><<<768, 256, 0, stream>>>(x0, h0, h1, h2, Wsu0, Wsu12, Wdt, bdt,
                                                  step, oscl, Pacc, rs, (float*)d_out);
    } else if (JC == 2) {
        attn_kernel<2><<<6 * 32 * 2, 256, 0, stream>>>(qn, kn, vT, m00, m20, m01, m11, m12, m22, Pacc, rs);
        update_kernel<2><<<768, 256, 0, stream>>>(x0, h0, h1, h2, Wsu0, Wsu12, Wdt, bdt,
                                                  step, oscl, Pacc, rs, (float*)d_out);
    } else {
        attn_kernel<1><<<6 * 32 * 1, 256, 0, stream>>>(qn, kn, vT, m00, m20, m01, m11, m12, m22, Pacc, rs);
        update_kernel<1><<<768, 256, 0, stream>>>(x0, h0, h1, h2, Wsu0, Wsu12, Wdt, bdt,
                                                  step, oscl, Pacc, rs, (float*)d_out);
    }
}